// Round 5
// baseline (201.456 us; speedup 1.0000x reference)
//
#include <hip/hip_runtime.h>
#include <hip/hip_bf16.h>

// GCN 2-layer forward on gfx950 — CSR radix partition, group-per-row packed
// fp16 gathers (no cross-lane reduction), fused fp16-MFMA MLP.
//
//   xh = fp16(dinv ⊙ x)            (row N = zeros, the OOB target; 128B rows)
//   t  = fp16( dinv[d] * Σ_{s∈csr[d]} xh[s] )     (gather, self-inclusive)
//   h  = relu(t W1 + b1)   [MFMA, C-frags in regs]
//   yhA/yhB = fp16(dinv ⊙ (h W2))  — SLAB layout: A = 64B rows (feats 0..31),
//             B = 16B rows (feats 32..39). No padding anywhere.
//   out[d] = dinv[d] * Σ yh[s] + b2               (gather)
//
// R16 (on R15 = 195.8us):
//  (1) yh slab split. R14 geometry fetched 128B/edge in gather2 but used 80B
//      (128B-aligned rows, 48B zero pad). R13's 80B-packed rows failed on
//      sector alignment. Slabs keep alignment AND kill the pad: per edge,
//      one aligned 64B line (slabA) + 16B from slabB (1.6MB, ~L2-resident).
//      gather2 miss traffic ~halves (89 -> ~50MB). k_mlp's 4.8MB pad-zero
//      writes are gone (no pad exists).
//  (2) ssrc software prefetch in both gathers: next batch's ssrc load issues
//      before this batch's row loads, hiding the ssrc miss latency under the
//      8 row loads + accumulate (was a serial ssrc->shfl->loads chain).

static constexpr int FIN = 64;
static constexpr int HID = 128;
static constexpr int CLS = 40;
static constexpr int NB_MAX = 392;   // buckets of 256 nodes; N <= 100352
static constexpr int NWG_P = 256;    // partition workgroups

typedef _Float16 half8 __attribute__((ext_vector_type(8)));
typedef _Float16 half4v __attribute__((ext_vector_type(4)));
typedef _Float16 half2v __attribute__((ext_vector_type(2)));
typedef float floatx4 __attribute__((ext_vector_type(4)));

// ---------------- CSR build: radix partition by dst>>8 ----------------

// Blocks 0..NWG_P-1: per-WG bucket histogram of dst.
// Blocks NWG_P..NWG_P+1: weight prep + OOB zero rows + gcur=0 (independent).
__global__ __launch_bounds__(1024) void k_cnt(const int* __restrict__ dst,
                                              int* __restrict__ cntmat,
                                              int E, int NB, int per_wg,
                                              const float* __restrict__ W1,
                                              const float* __restrict__ W2,
                                              _Float16* __restrict__ w1f,
                                              _Float16* __restrict__ w2f,
                                              _Float16* __restrict__ xh,
                                              _Float16* __restrict__ yhA,
                                              _Float16* __restrict__ yhB,
                                              int* __restrict__ gcur, int N) {
    __shared__ int lh[NB_MAX];
    const int tid = threadIdx.x, wg = blockIdx.x;
    if (wg < NWG_P) {
        for (int i = tid; i < NB; i += 1024) lh[i] = 0;
        __syncthreads();
        const int r0 = wg * per_wg, r1 = min(E, r0 + per_wg);
        for (int e = r0 + tid; e < r1; e += 1024)
            atomicAdd(&lh[dst[e] >> 8], 1);
        __syncthreads();
        for (int b = tid; b < NB; b += 1024) cntmat[b * NWG_P + wg] = lh[b];
        return;
    }
    // ---- prep blocks ----
    const int idx = (wg - NWG_P) * 1024 + tid;   // 0..2047
    if (idx < 1024) {                       // W1: nt 0..7, kk 0..1, lane
        const int lane = idx & 63;
        const int kk = (idx >> 6) & 1;
        const int nt = idx >> 7;
        const int quad = lane >> 4, col = lane & 15;
        half8 o;
#pragma unroll
        for (int j = 0; j < 8; ++j) {
            const int k = kk * 32 + quad * 8 + j;
            const int n = nt * 16 + col;
            o[j] = (_Float16)W1[k * HID + n];
        }
        *(half8*)(w1f + (size_t)idx * 8) = o;
    } else if (idx < 1024 + 768) {          // W2: nt 0..2, kk 0..3, lane (n pad 48)
        const int i2 = idx - 1024;
        const int lane = i2 & 63;
        const int kk = (i2 >> 6) & 3;
        const int nt = i2 >> 8;
        const int quad = lane >> 4, col = lane & 15;
        half8 o;
#pragma unroll
        for (int j = 0; j < 8; ++j) {
            const int k = kk * 32 + quad * 8 + j;
            const int n = nt * 16 + col;
            o[j] = (n < CLS) ? (_Float16)W2[k * CLS + n] : (_Float16)0.f;
        }
        *(half8*)(w2f + (size_t)i2 * 8) = o;
    } else if (idx < 1792 + 64) {           // zero OOB rows (index N)
        const int t = idx - 1792;
        xh[(size_t)N * 64 + t] = (_Float16)0;
        if (t < 32) yhA[(size_t)N * 32 + t] = (_Float16)0;
        if (t < 8)  yhB[(size_t)N * 8 + t] = (_Float16)0;
    } else if (idx == 1792 + 64) {
        *gcur = 0;
    }
}

// Per-bucket scan of cntmat row + ATOMIC region allocation (order-free):
// region [bbase[b], bbase[b] + btot[b] + 256) holds this bucket's tmp edges
// (first btot[b]) and ssrc entries (self + edges, interleaved by p2).
__global__ __launch_bounds__(256) void k_balloc(int* __restrict__ cntmat,
                                                int* __restrict__ bbase,
                                                int* __restrict__ btot,
                                                int* __restrict__ gcur) {
    __shared__ int sd[256];
    const int b = blockIdx.x, tid = threadIdx.x;
    int v = cntmat[b * NWG_P + tid];
    sd[tid] = v;
    for (int off = 1; off < 256; off <<= 1) {
        __syncthreads();
        int t = (tid >= off) ? sd[tid - off] : 0;
        __syncthreads();
        sd[tid] += t;
    }
    __syncthreads();
    cntmat[b * NWG_P + tid] = sd[tid] - v;
    if (tid == 255) {
        const int tot = sd[255];
        btot[b] = tot;
        bbase[b] = atomicAdd(gcur, tot + 256);
    }
}

__global__ __launch_bounds__(1024) void k_scat(const int* __restrict__ ei,
                                               const int* __restrict__ cntmat,
                                               const int* __restrict__ bbase,
                                               unsigned* __restrict__ tmp,
                                               int E, int NB, int per_wg) {
    __shared__ int lcur[NB_MAX];
    const int tid = threadIdx.x, wg = blockIdx.x;
    for (int b = tid; b < NB; b += 1024)
        lcur[b] = cntmat[b * NWG_P + wg] + bbase[b];
    __syncthreads();
    const int r0 = wg * per_wg, r1 = min(E, r0 + per_wg);
    for (int e = r0 + tid; e < r1; e += 1024) {
        int s = ei[e], d = ei[E + e];
        int b = d >> 8;
        int pos = atomicAdd(&lcur[b], 1);
        tmp[pos] = ((unsigned)(d & 255) << 24) | (unsigned)s;
    }
}

// P2: one WG per bucket. Self-inclusive adjacency; ssrc holds NODE indices.
// Bucket b's edges: tmp[e0 .. e0+btot[b]), region for ssrc entries:
// [e0, e0 + btot[b] + 256).
__global__ __launch_bounds__(256) void k_p2(const unsigned* __restrict__ tmp,
                                            const int* __restrict__ bbase,
                                            const int* __restrict__ btot,
                                            int* __restrict__ rstart,
                                            int* __restrict__ cnt,
                                            float* __restrict__ dinv,
                                            int* __restrict__ ssrc, int N) {
    __shared__ int nh[256];
    __shared__ int sd[256];
    __shared__ int curs[256];
    const int tid = threadIdx.x;
    const int b = blockIdx.x;
    const int node0 = b << 8;
    const int e0 = bbase[b], e1 = e0 + btot[b];
    nh[tid] = 0;
    __syncthreads();
    for (int e = e0 + tid; e < e1; e += 256)
        atomicAdd(&nh[tmp[e] >> 24], 1);
    __syncthreads();
    int v = nh[tid];
    sd[tid] = v;
    for (int off = 1; off < 256; off <<= 1) {
        __syncthreads();
        int t = (tid >= off) ? sd[tid - off] : 0;
        __syncthreads();
        sd[tid] += t;
    }
    __syncthreads();
    int rs = e0 + (sd[tid] - v) + tid;     // self + edges, within region
    int node = node0 + tid;
    if (node < N) {
        rstart[node] = rs;
        cnt[node] = v + 1;                 // self-inclusive
        dinv[node] = rsqrtf((float)v + 1.0f);
        ssrc[rs] = node;                   // self entry (node index)
    }
    curs[tid] = rs + 1;
    __syncthreads();
    for (int e = e0 + tid; e < e1; e += 256) {
        unsigned p = tmp[e];
        int slot = atomicAdd(&curs[p >> 24], 1);
        ssrc[slot] = (int)(p & 0xFFFFFFu);  // node index
    }
}

// ---------------- element-wise prep ----------------

// xh = fp16(dinv ⊙ x): 4 elems per thread. x is read-once -> nontemporal.
__global__ __launch_bounds__(256) void k_prescale(const float* __restrict__ x,
                                                  const float* __restrict__ dinv,
                                                  _Float16* __restrict__ xh, int N) {
    const int idx = blockIdx.x * 256 + threadIdx.x;   // over N*16
    if (idx >= N * 16) return;
    const int i = idx >> 4;
    const float dv = dinv[i];
    const floatx4 v = __builtin_nontemporal_load((const floatx4*)&x[(size_t)idx * 4]);
    half4v o;
    o[0] = (_Float16)(dv * v[0]); o[1] = (_Float16)(dv * v[1]);
    o[2] = (_Float16)(dv * v[2]); o[3] = (_Float16)(dv * v[3]);
    *(half4v*)(xh + (size_t)idx * 4) = o;   // temporal: gather1 wants it in L2
}

// ---------------- group-per-row packed fp16 gather ----------------
// Wave handles 8 rows: group g (8 lanes) owns row wave*8+g; lane owns a
// fixed 16B chunk; edges accumulate serially in-lane -> zero reduction.
// ssrc holds NODE indices; shfl broadcasts the node, each lane computes its
// chunk address. Loop bound is PER-GROUP (exec-masked divergence). ssrc for
// batch n+1 is prefetched before batch n's row loads (hides ssrc latency).
// SLAB=false: X rows are 128B (xh). SLAB=true: slabA = 64B rows (feats
// 0..31, subs 0..3), slabB = 16B rows (feats 32..39, subs 4..7 duplicate
// the same 16B — HW dedups the transaction; epilogue ignores subs 5..7).

template <bool HALF_OUT, int FOUT, bool BIAS, bool SLAB>
__global__ __launch_bounds__(256) void k_gather8(const _Float16* __restrict__ X,
                                                 const _Float16* __restrict__ XB,
                                                 const float* __restrict__ dinv,
                                                 const int* __restrict__ rstart,
                                                 const int* __restrict__ cnt,
                                                 const int* __restrict__ ssrc,
                                                 const float* __restrict__ bias,
                                                 void* __restrict__ outv,
                                                 int N) {
    const int wave = (blockIdx.x * 256 + threadIdx.x) >> 6;
    const int lane = threadIdx.x & 63;
    const int g = lane >> 3, sub = lane & 7;
    const int r = wave * 8 + g;
    const int rc = min(r, N - 1);
    const int st = rstart[rc];
    const int total = cnt[rc];             // self-inclusive, >= 1 (uniform per group)
    const char* Xb = (const char*)X;
    const char* Xb2 = (const char*)XB;
    half2v acc2[4] = {half2v{0, 0}, half2v{0, 0}, half2v{0, 0}, half2v{0, 0}};
    int cur = ssrc[st + min(sub, total - 1)];          // batch 0 prefetch
    for (int base = 0; base < total; base += 8) {
        const int idx = base + sub;
        const int myN = (idx < total) ? cur : N;       // OOB tail -> zero row
        cur = ssrc[st + min(base + 8 + sub, total - 1)]; // prefetch batch+1 (in-bounds)
#pragma unroll
        for (int jj = 0; jj < 8; ++jj) {
            const int nd = __shfl(myN, g * 8 + jj);
            half8 hv;
            if (SLAB) {
                hv = (sub < 4)
                   ? *(const half8*)(Xb + ((size_t)nd << 6) + (sub << 4))
                   : *(const half8*)(Xb2 + ((size_t)nd << 4));
            } else {
                hv = *(const half8*)(Xb + ((size_t)nd << 7) + (sub << 4));
            }
            const half2v* h2 = (const half2v*)&hv;
            acc2[0] += h2[0]; acc2[1] += h2[1];
            acc2[2] += h2[2]; acc2[3] += h2[3];
        }
    }
    if (r >= N) return;
    const float dv = dinv[r];
    float acc[8];
#pragma unroll
    for (int k = 0; k < 8; ++k) acc[k] = (float)acc2[k >> 1][k & 1] * dv;
    if (HALF_OUT) {
        half8 o;
#pragma unroll
        for (int k = 0; k < 8; ++k) o[k] = (_Float16)acc[k];
        *(half8*)((_Float16*)outv + ((size_t)r << 6) + (sub << 3)) = o;  // re-read by mlp: temporal
    } else {
        const int f0 = sub * 8;
        if (f0 < FOUT) {                   // subs 0..4 write (feats 0..39)
            if (BIAS) {
                float4 bb0 = *(const float4*)&bias[f0];
                float4 bb1 = *(const float4*)&bias[f0 + 4];
                acc[0] += bb0.x; acc[1] += bb0.y; acc[2] += bb0.z; acc[3] += bb0.w;
                acc[4] += bb1.x; acc[5] += bb1.y; acc[6] += bb1.z; acc[7] += bb1.w;
            }
            float* op = (float*)outv + (size_t)r * FOUT + f0;
            const floatx4 o0 = {acc[0], acc[1], acc[2], acc[3]};
            const floatx4 o1 = {acc[4], acc[5], acc[6], acc[7]};
            __builtin_nontemporal_store(o0, (floatx4*)op);      // out: write-once
            __builtin_nontemporal_store(o1, (floatx4*)(op + 4));
        }
    }
}

// ---------------- fused MFMA MLP: t -> h (regs) -> yh slabs ----------------

__global__ __launch_bounds__(256, 3) void k_mlp(const _Float16* __restrict__ th,
                                                const _Float16* __restrict__ w1f,
                                                const float* __restrict__ b1,
                                                const _Float16* __restrict__ w2f,
                                                const float* __restrict__ dinv,
                                                _Float16* __restrict__ yhA,
                                                _Float16* __restrict__ yhB, int N) {
    __shared__ _Float16 hbuf[4][16 * 128];  // 16 KB
    const int tid = threadIdx.x;
    const int wave = tid >> 6, lane = tid & 63;
    const int quad = lane >> 4, col = lane & 15;
    const int row0 = blockIdx.x * 64 + wave * 16;
    const int arow = min(row0 + col, N - 1);
    // th is dead after this kernel -> nontemporal (frees L2 for yh/ssrc)
    const half8 a0 = __builtin_nontemporal_load((const half8*)(th + ((size_t)arow << 6) + quad * 8));
    const half8 a1 = __builtin_nontemporal_load((const half8*)(th + ((size_t)arow << 6) + 32 + quad * 8));
    floatx4 c[8];
#pragma unroll
    for (int nt = 0; nt < 8; ++nt) {
        c[nt] = (floatx4){0.f, 0.f, 0.f, 0.f};
        const half8 bb0 = *(const half8*)(w1f + (size_t)((nt * 2 + 0) * 64 + lane) * 8);
        const half8 bb1 = *(const half8*)(w1f + (size_t)((nt * 2 + 1) * 64 + lane) * 8);
        c[nt] = __builtin_amdgcn_mfma_f32_16x16x32_f16(a0, bb0, c[nt], 0, 0, 0);
        c[nt] = __builtin_amdgcn_mfma_f32_16x16x32_f16(a1, bb1, c[nt], 0, 0, 0);
    }
    _Float16* hb = hbuf[wave];
#pragma unroll
    for (int nt = 0; nt < 8; ++nt) {
        const float bv = b1[nt * 16 + col];
#pragma unroll
        for (int reg = 0; reg < 4; ++reg) {
            const int rr = quad * 4 + reg;
            const int hcol = nt * 16 + col;
            const int chunk = ((hcol >> 3) ^ rr) & 15;
            hb[rr * 128 + chunk * 8 + (hcol & 7)] =
                (_Float16)fmaxf(c[nt][reg] + bv, 0.f);
        }
    }
    __syncthreads();
    half8 a2[4];
#pragma unroll
    for (int kk = 0; kk < 4; ++kk) {
        const int chunk = ((kk * 4 + quad) ^ col) & 15;
        a2[kk] = *(const half8*)(hb + col * 128 + chunk * 8);
    }
    floatx4 c2[3];
#pragma unroll
    for (int nt = 0; nt < 3; ++nt) {
        c2[nt] = (floatx4){0.f, 0.f, 0.f, 0.f};
#pragma unroll
        for (int kk = 0; kk < 4; ++kk) {
            const half8 bb = *(const half8*)(w2f + (size_t)((nt * 4 + kk) * 64 + lane) * 8);
            c2[nt] = __builtin_amdgcn_mfma_f32_16x16x32_f16(a2[kk], bb, c2[nt], 0, 0, 0);
        }
    }
#pragma unroll
    for (int reg = 0; reg < 4; ++reg) {
        const int gr = row0 + quad * 4 + reg;
        const float dvr = dinv[min(gr, N - 1)];
#pragma unroll
        for (int nt = 0; nt < 3; ++nt) {
            const int cc = nt * 16 + col;
            if (gr < N && cc < CLS) {
                const _Float16 v = (_Float16)(c2[nt][reg] * dvr);
                if (cc < 32) yhA[(size_t)gr * 32 + cc] = v;
                else         yhB[(size_t)gr * 8 + (cc - 32)] = v;
            }
        }
    }
    // no pad writes: slabs hold exactly 40 halves per row
}

// ---------------- launch ----------------

extern "C" void kernel_launch(void* const* d_in, const int* in_sizes, int n_in,
                              void* d_out, int out_size, void* d_ws, size_t ws_size,
                              hipStream_t stream) {
    const float* x  = (const float*)d_in[0];
    const int*   ei = (const int*)d_in[1];   // [2][E]
    const float* W1 = (const float*)d_in[2];
    const float* b1 = (const float*)d_in[3];
    const float* W2 = (const float*)d_in[4];
    const float* b2 = (const float*)d_in[5];
    float* out = (float*)d_out;

    const int N = in_sizes[0] / FIN;
    const int E = in_sizes[1] / 2;
    const int NB = (N + 255) >> 8;
    const int per_wg = (E + NWG_P - 1) / NWG_P;

    char* p = (char*)d_ws;
    auto alloc = [&](size_t bytes) {
        char* q = p;
        p += (bytes + 255) & ~(size_t)255;   // keep every array 256B-aligned
        return q;
    };
    float* dinv    = (float*)alloc((size_t)N * 4);
    _Float16* th   = (_Float16*)alloc((size_t)(N + 1) * 128);  // 128B rows
    _Float16* xh   = (_Float16*)alloc((size_t)(N + 1) * 128);  // 128B rows
    _Float16* yhA  = (_Float16*)alloc((size_t)(N + 1) * 64);   // 64B rows (feats 0..31)
    _Float16* yhB  = (_Float16*)alloc((size_t)(N + 1) * 16);   // 16B rows (feats 32..39)
    int* cnt       = (int*)alloc((size_t)N * 4);
    int* rstart    = (int*)alloc((size_t)N * 4);
    int* ssrc      = (int*)alloc(((size_t)E + (size_t)NB_MAX * 256) * 4);
    int* cntmat    = (int*)alloc((size_t)NB_MAX * NWG_P * 4);
    int* btot      = (int*)alloc((size_t)NB_MAX * 4);
    int* bbase     = (int*)alloc((size_t)NB_MAX * 4);
    int* gcur      = (int*)alloc(256);
    unsigned* tmp  = (unsigned*)alloc(((size_t)E + (size_t)NB_MAX * 256) * 4);
    _Float16* w1f  = (_Float16*)alloc(8192 * 2);
    _Float16* w2f  = (_Float16*)alloc(6144 * 2);

    dim3 blk(256);
    // CSR build + (prep/zrows/gcur in k_cnt's 2 extra blocks)
    hipLaunchKernelGGL(k_cnt,    dim3(NWG_P + 2), dim3(1024), 0, stream,
                       ei + E, cntmat, E, NB, per_wg, W1, W2, w1f, w2f, xh, yhA, yhB, gcur, N);
    hipLaunchKernelGGL(k_balloc, dim3(NB), blk, 0, stream, cntmat, bbase, btot, gcur);
    hipLaunchKernelGGL(k_scat,   dim3(NWG_P), dim3(1024), 0, stream, ei, cntmat, bbase, tmp, E, NB, per_wg);
    hipLaunchKernelGGL(k_p2,     dim3(NB), blk, 0, stream, tmp, bbase, btot, rstart, cnt, dinv, ssrc, N);
    // layer 1: prescale -> group-per-row gather (fp16 out, 128B rows)
    hipLaunchKernelGGL(k_prescale, dim3((N * 16 + 255) / 256), blk, 0, stream, x, dinv, xh, N);
    hipLaunchKernelGGL((k_gather8<true, FIN, false, false>), dim3((N + 31) / 32), blk, 0, stream,
                       xh, (const _Float16*)nullptr, dinv, rstart, cnt, ssrc,
                       (const float*)nullptr, (void*)th, N);
    // fused MFMA MLP: t -> h -> yh slabs
    hipLaunchKernelGGL(k_mlp, dim3((N + 63) / 64), blk, 0, stream, th, w1f, b1, w2f, dinv, yhA, yhB, N);
    // layer 2 aggregate + bias -> out (slab gather)
    hipLaunchKernelGGL((k_gather8<false, CLS, true, true>), dim3((N + 31) / 32), blk, 0, stream,
                       yhA, yhB, dinv, rstart, cnt, ssrc, b2, (void*)out, N);
}

// Round 6
// 198.883 us; speedup vs baseline: 1.0129x; 1.0129x over previous
//
#include <hip/hip_runtime.h>
#include <hip/hip_bf16.h>

// GCN 2-layer forward on gfx950 — CSR radix partition, group-per-row packed
// fp16 gathers (no cross-lane reduction), fused fp16-MFMA MLP.
//
//   xh = fp16(dinv ⊙ x)            (row N = zeros, the OOB target; 128B rows)
//   t  = fp16( dinv[d] * Σ_{s∈csr[d]} xh[s] )     (gather -> LDS, fused)
//   h  = relu(t W1 + b1)   [MFMA, C-frags in regs]
//   yh = fp16(dinv ⊙ (h W2)) padded to 64 cols (128B rows, cols 40..63 = 0)
//   out[d] = dinv[d] * Σ yh[s] + b2               (gather)
//
// R17 (on R15 = 195.8us; R16 slab split REVERTED — random gathers fetch
// granule-sized chunks regardless of packed footprint; 128B-aligned rows
// are optimal):
//  (1) gather1 + MLP fused (k_gmlp, 32 rows/block): t goes to chunk-swizzled
//      LDS (4KB) instead of global th — kills the 25.6MB th round-trip and
//      one launch. Waves 0/1 do the MFMA phase (tiles 0/1); waves 2/3 only
//      join barriers (MFMA is ~1% of the kernel). Layer1 computed in two
//      nt-halves to keep VGPR (and gather occupancy) up.
//  (2) k_prescale fused into k_p2's epilogue: dinv stashed in LDS, bucket's
//      256 contiguous x rows converted to xh with 16 threads/row (coalesced
//      float4). Kills one launch + the dinv global re-read.
//  8 -> 6 launches. Gather inner loops byte-identical to R15.

static constexpr int FIN = 64;
static constexpr int HID = 128;
static constexpr int CLS = 40;
static constexpr int NB_MAX = 392;   // buckets of 256 nodes; N <= 100352
static constexpr int NWG_P = 256;    // partition workgroups

typedef _Float16 half8 __attribute__((ext_vector_type(8)));
typedef _Float16 half4v __attribute__((ext_vector_type(4)));
typedef _Float16 half2v __attribute__((ext_vector_type(2)));
typedef float floatx4 __attribute__((ext_vector_type(4)));

// ---------------- CSR build: radix partition by dst>>8 ----------------

// Blocks 0..NWG_P-1: per-WG bucket histogram of dst.
// Blocks NWG_P..NWG_P+1: weight prep + OOB zero rows + gcur=0 (independent).
__global__ __launch_bounds__(1024) void k_cnt(const int* __restrict__ dst,
                                              int* __restrict__ cntmat,
                                              int E, int NB, int per_wg,
                                              const float* __restrict__ W1,
                                              const float* __restrict__ W2,
                                              _Float16* __restrict__ w1f,
                                              _Float16* __restrict__ w2f,
                                              _Float16* __restrict__ xh,
                                              _Float16* __restrict__ yh,
                                              int* __restrict__ gcur, int N) {
    __shared__ int lh[NB_MAX];
    const int tid = threadIdx.x, wg = blockIdx.x;
    if (wg < NWG_P) {
        for (int i = tid; i < NB; i += 1024) lh[i] = 0;
        __syncthreads();
        const int r0 = wg * per_wg, r1 = min(E, r0 + per_wg);
        for (int e = r0 + tid; e < r1; e += 1024)
            atomicAdd(&lh[dst[e] >> 8], 1);
        __syncthreads();
        for (int b = tid; b < NB; b += 1024) cntmat[b * NWG_P + wg] = lh[b];
        return;
    }
    // ---- prep blocks ----
    const int idx = (wg - NWG_P) * 1024 + tid;   // 0..2047
    if (idx < 1024) {                       // W1: nt 0..7, kk 0..1, lane
        const int lane = idx & 63;
        const int kk = (idx >> 6) & 1;
        const int nt = idx >> 7;
        const int quad = lane >> 4, col = lane & 15;
        half8 o;
#pragma unroll
        for (int j = 0; j < 8; ++j) {
            const int k = kk * 32 + quad * 8 + j;
            const int n = nt * 16 + col;
            o[j] = (_Float16)W1[k * HID + n];
        }
        *(half8*)(w1f + (size_t)idx * 8) = o;
    } else if (idx < 1024 + 768) {          // W2: nt 0..2, kk 0..3, lane (n pad 48)
        const int i2 = idx - 1024;
        const int lane = i2 & 63;
        const int kk = (i2 >> 6) & 3;
        const int nt = i2 >> 8;
        const int quad = lane >> 4, col = lane & 15;
        half8 o;
#pragma unroll
        for (int j = 0; j < 8; ++j) {
            const int k = kk * 32 + quad * 8 + j;
            const int n = nt * 16 + col;
            o[j] = (n < CLS) ? (_Float16)W2[k * CLS + n] : (_Float16)0.f;
        }
        *(half8*)(w2f + (size_t)i2 * 8) = o;
    } else if (idx < 1792 + 64) {           // zero OOB rows (index N)
        const int t = idx - 1792;
        xh[(size_t)N * 64 + t] = (_Float16)0;
        yh[(size_t)N * 64 + t] = (_Float16)0;
    } else if (idx == 1792 + 64) {
        *gcur = 0;
    }
}

// Per-bucket scan of cntmat row + ATOMIC region allocation (order-free):
// region [bbase[b], bbase[b] + btot[b] + 256) holds this bucket's tmp edges
// (first btot[b]) and ssrc entries (self + edges, interleaved by p2).
__global__ __launch_bounds__(256) void k_balloc(int* __restrict__ cntmat,
                                                int* __restrict__ bbase,
                                                int* __restrict__ btot,
                                                int* __restrict__ gcur) {
    __shared__ int sd[256];
    const int b = blockIdx.x, tid = threadIdx.x;
    int v = cntmat[b * NWG_P + tid];
    sd[tid] = v;
    for (int off = 1; off < 256; off <<= 1) {
        __syncthreads();
        int t = (tid >= off) ? sd[tid - off] : 0;
        __syncthreads();
        sd[tid] += t;
    }
    __syncthreads();
    cntmat[b * NWG_P + tid] = sd[tid] - v;
    if (tid == 255) {
        const int tot = sd[255];
        btot[b] = tot;
        bbase[b] = atomicAdd(gcur, tot + 256);
    }
}

__global__ __launch_bounds__(1024) void k_scat(const int* __restrict__ ei,
                                               const int* __restrict__ cntmat,
                                               const int* __restrict__ bbase,
                                               unsigned* __restrict__ tmp,
                                               int E, int NB, int per_wg) {
    __shared__ int lcur[NB_MAX];
    const int tid = threadIdx.x, wg = blockIdx.x;
    for (int b = tid; b < NB; b += 1024)
        lcur[b] = cntmat[b * NWG_P + wg] + bbase[b];
    __syncthreads();
    const int r0 = wg * per_wg, r1 = min(E, r0 + per_wg);
    for (int e = r0 + tid; e < r1; e += 1024) {
        int s = ei[e], d = ei[E + e];
        int b = d >> 8;
        int pos = atomicAdd(&lcur[b], 1);
        tmp[pos] = ((unsigned)(d & 255) << 24) | (unsigned)s;
    }
}

// P2: one WG per bucket. Self-inclusive adjacency; ssrc holds NODE indices.
// Bucket b's edges: tmp[e0 .. e0+btot[b]). Epilogue: prescale this bucket's
// 256 contiguous x rows -> xh (dinv from LDS), 16 threads/row coalesced.
__global__ __launch_bounds__(256) void k_p2(const unsigned* __restrict__ tmp,
                                            const int* __restrict__ bbase,
                                            const int* __restrict__ btot,
                                            int* __restrict__ rstart,
                                            int* __restrict__ cnt,
                                            float* __restrict__ dinv,
                                            int* __restrict__ ssrc,
                                            const float* __restrict__ x,
                                            _Float16* __restrict__ xh, int N) {
    __shared__ int nh[256];
    __shared__ int sd[256];
    __shared__ int curs[256];
    __shared__ float sdv[256];
    const int tid = threadIdx.x;
    const int b = blockIdx.x;
    const int node0 = b << 8;
    const int e0 = bbase[b], e1 = e0 + btot[b];
    nh[tid] = 0;
    __syncthreads();
    for (int e = e0 + tid; e < e1; e += 256)
        atomicAdd(&nh[tmp[e] >> 24], 1);
    __syncthreads();
    int v = nh[tid];
    sd[tid] = v;
    for (int off = 1; off < 256; off <<= 1) {
        __syncthreads();
        int t = (tid >= off) ? sd[tid - off] : 0;
        __syncthreads();
        sd[tid] += t;
    }
    __syncthreads();
    int rs = e0 + (sd[tid] - v) + tid;     // self + edges, within region
    int node = node0 + tid;
    const float dvv = rsqrtf((float)v + 1.0f);
    sdv[tid] = dvv;
    if (node < N) {
        rstart[node] = rs;
        cnt[node] = v + 1;                 // self-inclusive
        dinv[node] = dvv;
        ssrc[rs] = node;                   // self entry (node index)
    }
    curs[tid] = rs + 1;
    __syncthreads();                       // sdv + curs visible
    for (int e = e0 + tid; e < e1; e += 256) {
        unsigned p = tmp[e];
        int slot = atomicAdd(&curs[p >> 24], 1);
        ssrc[slot] = (int)(p & 0xFFFFFFu);  // node index
    }
    // ---- prescale epilogue: xh = fp16(dinv * x) for this bucket ----
    const int nrows = min(256, N - node0);
    const float* xb = x + (size_t)node0 * 64;
    _Float16* xhb = xh + (size_t)node0 * 64;
    const int rr = tid >> 4, cc = tid & 15;   // 16 rows x 16 thread-cols per iter
#pragma unroll 4
    for (int j = 0; j < 16; ++j) {
        const int row = j * 16 + rr;
        if (row < nrows) {
            const floatx4 vv = __builtin_nontemporal_load(
                (const floatx4*)(xb + (size_t)row * 64 + cc * 4));
            const float dvr = sdv[row];
            half4v o;
            o[0] = (_Float16)(dvr * vv[0]); o[1] = (_Float16)(dvr * vv[1]);
            o[2] = (_Float16)(dvr * vv[2]); o[3] = (_Float16)(dvr * vv[3]);
            *(half4v*)(xhb + (size_t)row * 64 + cc * 4) = o;
        }
    }
}

// ---------------- fused gather1 + MFMA MLP ----------------
// Block = 256 threads, 32 rows. Gather phase (all 4 waves): group g (8
// lanes) owns local row wave*8+g; lane owns a fixed 16B chunk; edges
// accumulate serially in-lane (R15 loop, per-group bound). Result scaled by
// dinv and stored fp16 into chunk-swizzled LDS tbuf (phys = (chunk ^
// (row&7))&7 — keeps MFMA-phase ds_read at the 8-cycle BW floor).
// MFMA phase: wave 0 -> rows 0..15, wave 1 -> rows 16..31; waves 2/3 only
// join barriers. Layer1 in two nt-halves (VGPR); h in per-wave hbuf with
// the existing XOR chunk swizzle; layer2 -> yh (128B rows, pad zeroed).

__global__ __launch_bounds__(256) void k_gmlp(const _Float16* __restrict__ xh,
                                              const float* __restrict__ dinv,
                                              const int* __restrict__ rstart,
                                              const int* __restrict__ cnt,
                                              const int* __restrict__ ssrc,
                                              const _Float16* __restrict__ w1f,
                                              const float* __restrict__ b1,
                                              const _Float16* __restrict__ w2f,
                                              _Float16* __restrict__ yh, int N) {
    __shared__ _Float16 tbuf[32 * 64];      // 4 KB, chunk-swizzled
    __shared__ _Float16 hbuf[2][16 * 128];  // 8 KB
    const int tid = threadIdx.x;
    const int wave = tid >> 6, lane = tid & 63;
    const int g = lane >> 3, sub = lane & 7;
    const int lr = wave * 8 + g;            // local row 0..31
    const int r = blockIdx.x * 32 + lr;
    const int rc = min(r, N - 1);
    const int st = rstart[rc];
    const int total = cnt[rc];              // self-inclusive, >= 1
    const char* Xb = (const char*)xh;
    half2v acc2[4] = {half2v{0, 0}, half2v{0, 0}, half2v{0, 0}, half2v{0, 0}};
    for (int base = 0; base < total; base += 8) {
        const int idx = base + sub;
        int myN = ssrc[st + min(idx, total - 1)];
        myN = (idx < total) ? myN : N;      // OOB tail -> zero row
        const int myO = myN << 7;           // 128B rows
#pragma unroll
        for (int jj = 0; jj < 8; ++jj) {
            const int off = __shfl(myO, g * 8 + jj);
            const half8 hv = *(const half8*)(Xb + off + (sub << 4));
            const half2v* h2 = (const half2v*)&hv;
            acc2[0] += h2[0]; acc2[1] += h2[1];
            acc2[2] += h2[2]; acc2[3] += h2[3];
        }
    }
    {   // scale + store t into swizzled LDS (always: r>=N rows hold junk, unused)
        const float dv = dinv[rc];
        half8 o;
#pragma unroll
        for (int k = 0; k < 8; ++k) o[k] = (_Float16)((float)acc2[k >> 1][k & 1] * dv);
        *(half8*)(tbuf + lr * 64 + (((sub ^ (lr & 7)) & 7) << 3)) = o;
    }
    __syncthreads();
    // ---- MFMA phase ----
    const int quad = lane >> 4, col = lane & 15;
    if (wave < 2) {
        const int tile = wave;
        const int lrow = tile * 16 + col;
        const int pc0 = (quad ^ (col & 7)) & 7;
        const half8 a0 = *(const half8*)(tbuf + lrow * 64 + (pc0 << 3));
        const half8 a1 = *(const half8*)(tbuf + lrow * 64 + ((pc0 ^ 4) << 3));
        _Float16* hb = hbuf[wave];
#pragma unroll
        for (int hf = 0; hf < 2; ++hf) {    // layer1 in two nt-halves (VGPR)
            floatx4 c[4];
#pragma unroll
            for (int n4 = 0; n4 < 4; ++n4) {
                const int nt = hf * 4 + n4;
                c[n4] = (floatx4){0.f, 0.f, 0.f, 0.f};
                const half8 bb0 = *(const half8*)(w1f + (size_t)((nt * 2 + 0) * 64 + lane) * 8);
                const half8 bb1 = *(const half8*)(w1f + (size_t)((nt * 2 + 1) * 64 + lane) * 8);
                c[n4] = __builtin_amdgcn_mfma_f32_16x16x32_f16(a0, bb0, c[n4], 0, 0, 0);
                c[n4] = __builtin_amdgcn_mfma_f32_16x16x32_f16(a1, bb1, c[n4], 0, 0, 0);
            }
#pragma unroll
            for (int n4 = 0; n4 < 4; ++n4) {
                const int nt = hf * 4 + n4;
                const float bv = b1[nt * 16 + col];
#pragma unroll
                for (int reg = 0; reg < 4; ++reg) {
                    const int rr2 = quad * 4 + reg;
                    const int hcol = nt * 16 + col;
                    const int chunk = ((hcol >> 3) ^ rr2) & 15;
                    hb[rr2 * 128 + chunk * 8 + (hcol & 7)] =
                        (_Float16)fmaxf(c[n4][reg] + bv, 0.f);
                }
            }
        }
    }
    __syncthreads();                        // order hbuf write -> read
    if (wave < 2) {
        const int tile = wave;
        const _Float16* hb = hbuf[wave];
        half8 a2[4];
#pragma unroll
        for (int kk = 0; kk < 4; ++kk) {
            const int chunk = ((kk * 4 + quad) ^ col) & 15;
            a2[kk] = *(const half8*)(hb + col * 128 + chunk * 8);
        }
        floatx4 c2[3];
#pragma unroll
        for (int nt = 0; nt < 3; ++nt) {
            c2[nt] = (floatx4){0.f, 0.f, 0.f, 0.f};
#pragma unroll
            for (int kk = 0; kk < 4; ++kk) {
                const half8 bb = *(const half8*)(w2f + (size_t)((nt * 4 + kk) * 64 + lane) * 8);
                c2[nt] = __builtin_amdgcn_mfma_f32_16x16x32_f16(a2[kk], bb, c2[nt], 0, 0, 0);
            }
        }
        const int grow0 = blockIdx.x * 32 + tile * 16;
#pragma unroll
        for (int reg = 0; reg < 4; ++reg) {
            const int gr = grow0 + quad * 4 + reg;
            const float dvr = dinv[min(gr, N - 1)];
#pragma unroll
            for (int nt = 0; nt < 3; ++nt) {
                const int cc = nt * 16 + col;
                if (gr < N && cc < CLS)
                    yh[((size_t)gr << 6) + cc] = (_Float16)(c2[nt][reg] * dvr);
            }
        }
        // zero pad cols 40..63 (12 dwords per row)
        for (int i = lane; i < 16 * 12; i += 64) {
            const int row = grow0 + i / 12;
            if (row < N)
                ((unsigned*)(yh + ((size_t)row << 6)))[20 + i % 12] = 0u;
        }
    }
}

// ---------------- group-per-row packed fp16 gather (layer 2) ----------------
// X: fp16 rows of 128B, row N = zeros. Identical inner loop to R15.

template <bool HALF_OUT, int FOUT, bool BIAS>
__global__ __launch_bounds__(256) void k_gather8(const _Float16* __restrict__ X,
                                                 const float* __restrict__ dinv,
                                                 const int* __restrict__ rstart,
                                                 const int* __restrict__ cnt,
                                                 const int* __restrict__ ssrc,
                                                 const float* __restrict__ bias,
                                                 void* __restrict__ outv,
                                                 int N) {
    const int wave = (blockIdx.x * 256 + threadIdx.x) >> 6;
    const int lane = threadIdx.x & 63;
    const int g = lane >> 3, sub = lane & 7;
    const int r = wave * 8 + g;
    const int rc = min(r, N - 1);
    const int st = rstart[rc];
    const int total = cnt[rc];             // self-inclusive, >= 1 (uniform per group)
    const char* Xb = (const char*)X;
    half2v acc2[4] = {half2v{0, 0}, half2v{0, 0}, half2v{0, 0}, half2v{0, 0}};
    for (int base = 0; base < total; base += 8) {
        const int idx = base + sub;
        int myN = ssrc[st + min(idx, total - 1)];
        myN = (idx < total) ? myN : N;     // OOB tail -> zero row
        const int myO = myN << 7;          // 128B rows
#pragma unroll
        for (int jj = 0; jj < 8; ++jj) {
            const int off = __shfl(myO, g * 8 + jj);
            const half8 hv = *(const half8*)(Xb + off + (sub << 4));
            const half2v* h2 = (const half2v*)&hv;
            acc2[0] += h2[0]; acc2[1] += h2[1];
            acc2[2] += h2[2]; acc2[3] += h2[3];
        }
    }
    if (r >= N) return;
    const float dv = dinv[r];
    float acc[8];
#pragma unroll
    for (int k = 0; k < 8; ++k) acc[k] = (float)acc2[k >> 1][k & 1] * dv;
    if (HALF_OUT) {
        half8 o;
#pragma unroll
        for (int k = 0; k < 8; ++k) o[k] = (_Float16)acc[k];
        *(half8*)((_Float16*)outv + ((size_t)r << 6) + (sub << 3)) = o;
    } else {
        const int f0 = sub * 8;
        if (f0 < FOUT) {
            if (BIAS) {
                float4 bb0 = *(const float4*)&bias[f0];
                float4 bb1 = *(const float4*)&bias[f0 + 4];
                acc[0] += bb0.x; acc[1] += bb0.y; acc[2] += bb0.z; acc[3] += bb0.w;
                acc[4] += bb1.x; acc[5] += bb1.y; acc[6] += bb1.z; acc[7] += bb1.w;
            }
            float* op = (float*)outv + (size_t)r * FOUT + f0;
            const floatx4 o0 = {acc[0], acc[1], acc[2], acc[3]};
            const floatx4 o1 = {acc[4], acc[5], acc[6], acc[7]};
            __builtin_nontemporal_store(o0, (floatx4*)op);      // out: write-once
            __builtin_nontemporal_store(o1, (floatx4*)(op + 4));
        }
    }
}

// ---------------- launch ----------------

extern "C" void kernel_launch(void* const* d_in, const int* in_sizes, int n_in,
                              void* d_out, int out_size, void* d_ws, size_t ws_size,
                              hipStream_t stream) {
    const float* x  = (const float*)d_in[0];
    const int*   ei = (const int*)d_in[1];   // [2][E]
    const float* W1 = (const float*)d_in[2];
    const float* b1 = (const float*)d_in[3];
    const float* W2 = (const float*)d_in[4];
    const float* b2 = (const float*)d_in[5];
    float* out = (float*)d_out;

    const int N = in_sizes[0] / FIN;
    const int E = in_sizes[1] / 2;
    const int NB = (N + 255) >> 8;
    const int per_wg = (E + NWG_P - 1) / NWG_P;

    char* p = (char*)d_ws;
    auto alloc = [&](size_t bytes) {
        char* q = p;
        p += (bytes + 255) & ~(size_t)255;   // keep every array 256B-aligned
        return q;
    };
    float* dinv    = (float*)alloc((size_t)N * 4);
    _Float16* xh   = (_Float16*)alloc((size_t)(N + 1) * 128);  // 128B rows
    _Float16* yh   = (_Float16*)alloc((size_t)(N + 1) * 128);  // 128B rows
    int* cnt       = (int*)alloc((size_t)N * 4);
    int* rstart    = (int*)alloc((size_t)N * 4);
    int* ssrc      = (int*)alloc(((size_t)E + (size_t)NB_MAX * 256) * 4);
    int* cntmat    = (int*)alloc((size_t)NB_MAX * NWG_P * 4);
    int* btot      = (int*)alloc((size_t)NB_MAX * 4);
    int* bbase     = (int*)alloc((size_t)NB_MAX * 4);
    int* gcur      = (int*)alloc(256);
    unsigned* tmp  = (unsigned*)alloc(((size_t)E + (size_t)NB_MAX * 256) * 4);
    _Float16* w1f  = (_Float16*)alloc(8192 * 2);
    _Float16* w2f  = (_Float16*)alloc(6144 * 2);

    dim3 blk(256);
    // CSR build + (prep/zrows/gcur in k_cnt's 2 extra blocks)
    hipLaunchKernelGGL(k_cnt,    dim3(NWG_P + 2), dim3(1024), 0, stream,
                       ei + E, cntmat, E, NB, per_wg, W1, W2, w1f, w2f, xh, yh, gcur, N);
    hipLaunchKernelGGL(k_balloc, dim3(NB), blk, 0, stream, cntmat, bbase, btot, gcur);
    hipLaunchKernelGGL(k_scat,   dim3(NWG_P), dim3(1024), 0, stream, ei, cntmat, bbase, tmp, E, NB, per_wg);
    hipLaunchKernelGGL(k_p2,     dim3(NB), blk, 0, stream, tmp, bbase, btot, rstart, cnt, dinv, ssrc, x, xh, N);
    // fused layer1 gather + MLP: xh -> (t in LDS) -> yh
    hipLaunchKernelGGL(k_gmlp, dim3((N + 31) / 32), blk, 0, stream,
                       xh, dinv, rstart, cnt, ssrc, w1f, b1, w2f, yh, N);
    // layer 2 aggregate + bias -> out
    hipLaunchKernelGGL((k_gather8<false, CLS, true>), dim3((N + 31) / 32), blk, 0, stream,
                       yh, dinv, rstart, cnt, ssrc, b2, (void*)out, N);
}